// Round 1
// baseline (929.384 us; speedup 1.0000x reference)
//
#include <hip/hip_runtime.h>
#include <hip/hip_bf16.h>

// GAT encoder: 2 layers.
// L1: h1 = x@W1^T (N,4,64); attn softmax per dst over E+N edges (self-loops);
//     act1 = ELU(aggregate + b1)  -> (N,256)
// L2: h2 = act1@W2^T (N,64); attn; out = aggregate + b2 -> (N,64)
// Constants fixed by the model: IN=256, H1=4, D=64 (HID1=256), OUT=64.

#define NEG_SLOPE 0.2f
#define SM_EPS 1e-16f

// ---------------- fp32 GEMM: C[M,Ncols] = A[M,K] @ B[Ncols,K]^T ----------------
// BM=64, BN=64, BK=32, 256 threads, 4x4 per-thread tile.
__global__ __launch_bounds__(256) void gemm_abT(const float* __restrict__ A,
                                                const float* __restrict__ B,
                                                float* __restrict__ C,
                                                int M, int Ncols, int K) {
  __shared__ float As[32][68];  // [k][m], pad 4 keeps 16B alignment, 4-way write conflict ok
  __shared__ float Bs[32][68];  // [k][n]
  const int t = threadIdx.x;
  const int tm = t >> 4, tn = t & 15;
  const int row0 = blockIdx.x * 64, col0 = blockIdx.y * 64;
  float acc[4][4] = {};
  for (int k0 = 0; k0 < K; k0 += 32) {
    // A tile: 64 rows x 32 k = 512 float4, 2 per thread
#pragma unroll
    for (int i = 0; i < 2; ++i) {
      int lid = t + i * 256;          // 0..511
      int ar = lid >> 3;              // row within tile
      int ac = (lid & 7) << 2;        // k within tile (x4)
      float4 v = make_float4(0.f, 0.f, 0.f, 0.f);
      int gr = row0 + ar;
      if (gr < M) v = *reinterpret_cast<const float4*>(&A[(size_t)gr * K + k0 + ac]);
      As[ac + 0][ar] = v.x; As[ac + 1][ar] = v.y; As[ac + 2][ar] = v.z; As[ac + 3][ar] = v.w;
      // B tile (Ncols is a multiple of 64 here: 256 or 64)
      float4 w = *reinterpret_cast<const float4*>(&B[(size_t)(col0 + ar) * K + k0 + ac]);
      Bs[ac + 0][ar] = w.x; Bs[ac + 1][ar] = w.y; Bs[ac + 2][ar] = w.z; Bs[ac + 3][ar] = w.w;
    }
    __syncthreads();
#pragma unroll
    for (int k = 0; k < 32; ++k) {
      float4 a = *reinterpret_cast<const float4*>(&As[k][tm * 4]);
      float4 b = *reinterpret_cast<const float4*>(&Bs[k][tn * 4]);
      acc[0][0] = fmaf(a.x, b.x, acc[0][0]); acc[0][1] = fmaf(a.x, b.y, acc[0][1]);
      acc[0][2] = fmaf(a.x, b.z, acc[0][2]); acc[0][3] = fmaf(a.x, b.w, acc[0][3]);
      acc[1][0] = fmaf(a.y, b.x, acc[1][0]); acc[1][1] = fmaf(a.y, b.y, acc[1][1]);
      acc[1][2] = fmaf(a.y, b.z, acc[1][2]); acc[1][3] = fmaf(a.y, b.w, acc[1][3]);
      acc[2][0] = fmaf(a.z, b.x, acc[2][0]); acc[2][1] = fmaf(a.z, b.y, acc[2][1]);
      acc[2][2] = fmaf(a.z, b.z, acc[2][2]); acc[2][3] = fmaf(a.z, b.w, acc[2][3]);
      acc[3][0] = fmaf(a.w, b.x, acc[3][0]); acc[3][1] = fmaf(a.w, b.y, acc[3][1]);
      acc[3][2] = fmaf(a.w, b.z, acc[3][2]); acc[3][3] = fmaf(a.w, b.w, acc[3][3]);
    }
    __syncthreads();
  }
#pragma unroll
  for (int i = 0; i < 4; ++i) {
    int r = row0 + tm * 4 + i;
    if (r < M) {
      float4 v = make_float4(acc[i][0], acc[i][1], acc[i][2], acc[i][3]);
      *reinterpret_cast<float4*>(&C[(size_t)r * Ncols + col0 + tn * 4]) = v;
    }
  }
}

// ---------------- CSR build ----------------
__global__ void count_kernel(const int* __restrict__ ei, int E, int N, int* __restrict__ counts) {
  int e = blockIdx.x * blockDim.x + threadIdx.x;
  if (e >= E + N) return;
  int d = (e < E) ? ei[E + e] : (e - E);
  atomicAdd(&counts[d], 1);
}

__global__ __launch_bounds__(1024) void scan_kernel(const int* __restrict__ counts,
                                                    int* __restrict__ rowptr,
                                                    int* __restrict__ cursor, int N) {
  __shared__ int lds[1024];
  __shared__ int carry_s;
  const int t = threadIdx.x;
  if (t == 0) carry_s = 0;
  __syncthreads();
  for (int base = 0; base < N; base += 1024) {
    int i = base + t;
    int v = (i < N) ? counts[i] : 0;
    lds[t] = v;
    __syncthreads();
    for (int off = 1; off < 1024; off <<= 1) {
      int add = (t >= off) ? lds[t - off] : 0;
      __syncthreads();
      lds[t] += add;
      __syncthreads();
    }
    int incl = lds[t];
    int carry = carry_s;
    if (i < N) {
      int ex = carry + incl - v;
      rowptr[i] = ex;
      cursor[i] = ex;
    }
    __syncthreads();
    if (t == 1023) carry_s = carry + lds[1023];
    __syncthreads();
  }
  if (t == 0) rowptr[N] = carry_s;
}

__global__ void scatter_kernel(const int* __restrict__ ei, int E, int N,
                               int* __restrict__ cursor, int* __restrict__ srcs) {
  int e = blockIdx.x * blockDim.x + threadIdx.x;
  if (e >= E + N) return;
  int s = (e < E) ? ei[e] : (e - E);
  int d = (e < E) ? ei[E + e] : (e - E);
  int pos = atomicAdd(&cursor[d], 1);
  srcs[pos] = s;
}

// ---------------- attention logits: as[n,h] = <h[n,h,:], a_src[h,:]> ----------------
__global__ void alphas_kernel(const float* __restrict__ hmat, const float* __restrict__ a_src,
                              const float* __restrict__ a_dst, float* __restrict__ as_out,
                              float* __restrict__ ad_out, int N, int H) {
  int wave = threadIdx.x >> 6, lane = threadIdx.x & 63;
  int n = blockIdx.x * 4 + wave;
  if (n >= N) return;
  const float* row = hmat + (size_t)n * H * 64;
  for (int h = 0; h < H; ++h) {
    float v = row[h * 64 + lane];
    float ps = v * a_src[h * 64 + lane];
    float pd = v * a_dst[h * 64 + lane];
#pragma unroll
    for (int off = 32; off; off >>= 1) {
      ps += __shfl_xor(ps, off);
      pd += __shfl_xor(pd, off);
    }
    if (lane == 0) {
      as_out[(size_t)n * H + h] = ps;
      ad_out[(size_t)n * H + h] = pd;
    }
  }
}

// ---------------- layer-1 aggregate: block(256)=node, thread=channel; fuses +b1 and ELU ----
__global__ __launch_bounds__(256) void agg1_kernel(const float* __restrict__ h1,
                                                   const int* __restrict__ rowptr,
                                                   const int* __restrict__ srcs,
                                                   const float* __restrict__ as1,
                                                   const float* __restrict__ ad1,
                                                   const float* __restrict__ b1,
                                                   float* __restrict__ act1, int N) {
  const int n = blockIdx.x;
  const int tid = threadIdx.x;
  const int h = tid >> 6;
  const int beg = rowptr[n], end = rowptr[n + 1];
  const float ad = ad1[(size_t)n * 4 + h];
  float mmax = -1e30f;
  for (int j = beg; j < end; ++j) {
    float e = as1[(size_t)srcs[j] * 4 + h] + ad;
    e = e > 0.f ? e : NEG_SLOPE * e;
    mmax = fmaxf(mmax, e);
  }
  float ssum = 0.f;
  for (int j = beg; j < end; ++j) {
    float e = as1[(size_t)srcs[j] * 4 + h] + ad;
    e = e > 0.f ? e : NEG_SLOPE * e;
    ssum += __expf(e - mmax);
  }
  const float rs = 1.f / (ssum + SM_EPS);
  float acc = 0.f;
  for (int j = beg; j < end; ++j) {
    int s = srcs[j];
    float e = as1[(size_t)s * 4 + h] + ad;
    e = e > 0.f ? e : NEG_SLOPE * e;
    float w = __expf(e - mmax) * rs;
    acc = fmaf(w, h1[(size_t)s * 256 + tid], acc);
  }
  float o = acc + b1[tid];
  act1[(size_t)n * 256 + tid] = o > 0.f ? o : __expf(o) - 1.f;
}

// ---------------- layer-2 aggregate: wave=node (D=64), fuses +b2 ----------------
__global__ __launch_bounds__(256) void agg2_kernel(const float* __restrict__ h2,
                                                   const int* __restrict__ rowptr,
                                                   const int* __restrict__ srcs,
                                                   const float* __restrict__ as2,
                                                   const float* __restrict__ ad2,
                                                   const float* __restrict__ b2,
                                                   float* __restrict__ out, int N) {
  const int wave = threadIdx.x >> 6, lane = threadIdx.x & 63;
  const int n = blockIdx.x * 4 + wave;
  if (n >= N) return;
  const int beg = rowptr[n], end = rowptr[n + 1];
  const float ad = ad2[n];
  float mmax = -1e30f;
  for (int j = beg; j < end; ++j) {
    float e = as2[srcs[j]] + ad;
    e = e > 0.f ? e : NEG_SLOPE * e;
    mmax = fmaxf(mmax, e);
  }
  float ssum = 0.f;
  for (int j = beg; j < end; ++j) {
    float e = as2[srcs[j]] + ad;
    e = e > 0.f ? e : NEG_SLOPE * e;
    ssum += __expf(e - mmax);
  }
  const float rs = 1.f / (ssum + SM_EPS);
  float acc = 0.f;
  for (int j = beg; j < end; ++j) {
    int s = srcs[j];
    float e = as2[s] + ad;
    e = e > 0.f ? e : NEG_SLOPE * e;
    float w = __expf(e - mmax) * rs;
    acc = fmaf(w, h2[(size_t)s * 64 + lane], acc);
  }
  out[(size_t)n * 64 + lane] = acc + b2[lane];
}

extern "C" void kernel_launch(void* const* d_in, const int* in_sizes, int n_in,
                              void* d_out, int out_size, void* d_ws, size_t ws_size,
                              hipStream_t stream) {
  const float* x      = (const float*)d_in[0];
  const int*   ei     = (const int*)d_in[1];
  const float* W1     = (const float*)d_in[2];
  const float* a_src1 = (const float*)d_in[3];
  const float* a_dst1 = (const float*)d_in[4];
  const float* b1     = (const float*)d_in[5];
  const float* W2     = (const float*)d_in[6];
  const float* a_src2 = (const float*)d_in[7];
  const float* a_dst2 = (const float*)d_in[8];
  const float* b2     = (const float*)d_in[9];
  float* out = (float*)d_out;

  const int N = in_sizes[0] / 256;  // 50000
  const int E = in_sizes[1] / 2;    // 800000
  const int Etot = E + N;           // with self-loops
  const int K = 256;

  // workspace layout (~109 MB)
  char* ws = (char*)d_ws;
  size_t off = 0;
  auto alloc = [&](size_t bytes) -> void* {
    off = (off + 255) & ~(size_t)255;
    void* p = ws + off;
    off += bytes;
    return p;
  };
  float* h1     = (float*)alloc((size_t)N * 256 * 4);  // also reused as h2 (N*64) after L1
  float* act1   = (float*)alloc((size_t)N * 256 * 4);
  float* as1    = (float*)alloc((size_t)N * 4 * 4);
  float* ad1    = (float*)alloc((size_t)N * 4 * 4);
  float* as2    = (float*)alloc((size_t)N * 4);
  float* ad2    = (float*)alloc((size_t)N * 4);
  int*   counts = (int*)alloc((size_t)N * 4);
  int*   rowptr = (int*)alloc((size_t)(N + 1) * 4);
  int*   cursor = (int*)alloc((size_t)N * 4);
  int*   srcs   = (int*)alloc((size_t)Etot * 4);
  (void)ws_size; (void)n_in; (void)out_size;

  // CSR build (shared by both layers)
  hipMemsetAsync(counts, 0, (size_t)N * 4, stream);
  int ethreads = 256, eblocks = (Etot + 255) / 256;
  count_kernel<<<eblocks, ethreads, 0, stream>>>(ei, E, N, counts);
  scan_kernel<<<1, 1024, 0, stream>>>(counts, rowptr, cursor, N);
  scatter_kernel<<<eblocks, ethreads, 0, stream>>>(ei, E, N, cursor, srcs);

  // Layer 1
  {
    dim3 grid((N + 63) / 64, 256 / 64);
    gemm_abT<<<grid, 256, 0, stream>>>(x, W1, h1, N, 256, K);
  }
  alphas_kernel<<<(N + 3) / 4, 256, 0, stream>>>(h1, a_src1, a_dst1, as1, ad1, N, 4);
  agg1_kernel<<<N, 256, 0, stream>>>(h1, rowptr, srcs, as1, ad1, b1, act1, N);

  // Layer 2 (h2 aliases h1 storage; h1 is dead after agg1)
  float* h2 = h1;
  {
    dim3 grid((N + 63) / 64, 64 / 64);
    gemm_abT<<<grid, 256, 0, stream>>>(act1, W2, h2, N, 64, K);
  }
  alphas_kernel<<<(N + 3) / 4, 256, 0, stream>>>(h2, a_src2, a_dst2, as2, ad2, N, 1);
  agg2_kernel<<<(N + 3) / 4, 256, 0, stream>>>(h2, rowptr, srcs, as2, ad2, b2, out, N);
}

// Round 2
// 541.420 us; speedup vs baseline: 1.7166x; 1.7166x over previous
//
#include <hip/hip_runtime.h>
#include <hip/hip_bf16.h>

// GAT encoder: 2 layers.
// L1: h1 = x@W1^T (N,4,64); attn softmax per dst over E+N edges (self-loops);
//     act1 = ELU(aggregate + b1)  -> (N,256)
// L2: h2 = act1@W2^T (N,64); attn; out = aggregate + b2 -> (N,64)
// Constants: IN=256, H1=4, D=64 (HID1=256), OUT=64.

#define NEG_SLOPE 0.2f
#define SM_EPS 1e-16f

// ---------------- fp32 GEMM: C[M,Ncols] = A[M,K] @ B[Ncols,K]^T ----------------
__global__ __launch_bounds__(256) void gemm_abT(const float* __restrict__ A,
                                                const float* __restrict__ B,
                                                float* __restrict__ C,
                                                int M, int Ncols, int K) {
  __shared__ float As[32][68];
  __shared__ float Bs[32][68];
  const int t = threadIdx.x;
  const int tm = t >> 4, tn = t & 15;
  const int row0 = blockIdx.x * 64, col0 = blockIdx.y * 64;
  float acc[4][4] = {};
  for (int k0 = 0; k0 < K; k0 += 32) {
#pragma unroll
    for (int i = 0; i < 2; ++i) {
      int lid = t + i * 256;
      int ar = lid >> 3;
      int ac = (lid & 7) << 2;
      float4 v = make_float4(0.f, 0.f, 0.f, 0.f);
      int gr = row0 + ar;
      if (gr < M) v = *reinterpret_cast<const float4*>(&A[(size_t)gr * K + k0 + ac]);
      As[ac + 0][ar] = v.x; As[ac + 1][ar] = v.y; As[ac + 2][ar] = v.z; As[ac + 3][ar] = v.w;
      float4 w = *reinterpret_cast<const float4*>(&B[(size_t)(col0 + ar) * K + k0 + ac]);
      Bs[ac + 0][ar] = w.x; Bs[ac + 1][ar] = w.y; Bs[ac + 2][ar] = w.z; Bs[ac + 3][ar] = w.w;
    }
    __syncthreads();
#pragma unroll
    for (int k = 0; k < 32; ++k) {
      float4 a = *reinterpret_cast<const float4*>(&As[k][tm * 4]);
      float4 b = *reinterpret_cast<const float4*>(&Bs[k][tn * 4]);
      acc[0][0] = fmaf(a.x, b.x, acc[0][0]); acc[0][1] = fmaf(a.x, b.y, acc[0][1]);
      acc[0][2] = fmaf(a.x, b.z, acc[0][2]); acc[0][3] = fmaf(a.x, b.w, acc[0][3]);
      acc[1][0] = fmaf(a.y, b.x, acc[1][0]); acc[1][1] = fmaf(a.y, b.y, acc[1][1]);
      acc[1][2] = fmaf(a.y, b.z, acc[1][2]); acc[1][3] = fmaf(a.y, b.w, acc[1][3]);
      acc[2][0] = fmaf(a.z, b.x, acc[2][0]); acc[2][1] = fmaf(a.z, b.y, acc[2][1]);
      acc[2][2] = fmaf(a.z, b.z, acc[2][2]); acc[2][3] = fmaf(a.z, b.w, acc[2][3]);
      acc[3][0] = fmaf(a.w, b.x, acc[3][0]); acc[3][1] = fmaf(a.w, b.y, acc[3][1]);
      acc[3][2] = fmaf(a.w, b.z, acc[3][2]); acc[3][3] = fmaf(a.w, b.w, acc[3][3]);
    }
    __syncthreads();
  }
#pragma unroll
  for (int i = 0; i < 4; ++i) {
    int r = row0 + tm * 4 + i;
    if (r < M) {
      float4 v = make_float4(acc[i][0], acc[i][1], acc[i][2], acc[i][3]);
      *reinterpret_cast<float4*>(&C[(size_t)r * Ncols + col0 + tn * 4]) = v;
    }
  }
}

// ---------------- CSR build ----------------
__global__ void count_kernel(const int* __restrict__ ei, int E, int N, int* __restrict__ counts) {
  int e = blockIdx.x * blockDim.x + threadIdx.x;
  if (e >= E + N) return;
  int d = (e < E) ? ei[E + e] : (e - E);
  atomicAdd(&counts[d], 1);
}

__global__ __launch_bounds__(1024) void scan_kernel(const int* __restrict__ counts,
                                                    int* __restrict__ rowptr,
                                                    int* __restrict__ cursor, int N) {
  __shared__ int lds[1024];
  __shared__ int carry_s;
  const int t = threadIdx.x;
  if (t == 0) carry_s = 0;
  __syncthreads();
  for (int base = 0; base < N; base += 1024) {
    int i = base + t;
    int v = (i < N) ? counts[i] : 0;
    lds[t] = v;
    __syncthreads();
    for (int off = 1; off < 1024; off <<= 1) {
      int add = (t >= off) ? lds[t - off] : 0;
      __syncthreads();
      lds[t] += add;
      __syncthreads();
    }
    int incl = lds[t];
    int carry = carry_s;
    if (i < N) {
      int ex = carry + incl - v;
      rowptr[i] = ex;
      cursor[i] = ex;
    }
    __syncthreads();
    if (t == 1023) carry_s = carry + lds[1023];
    __syncthreads();
  }
  if (t == 0) rowptr[N] = carry_s;
}

__global__ void scatter_kernel(const int* __restrict__ ei, int E, int N,
                               int* __restrict__ cursor, int* __restrict__ srcs,
                               int* __restrict__ dsts) {
  int e = blockIdx.x * blockDim.x + threadIdx.x;
  if (e >= E + N) return;
  int s = (e < E) ? ei[e] : (e - E);
  int d = (e < E) ? ei[E + e] : (e - E);
  int pos = atomicAdd(&cursor[d], 1);
  srcs[pos] = s;
  dsts[pos] = d;
}

// ---------------- attention logits per node ----------------
__global__ void alphas_kernel(const float* __restrict__ hmat, const float* __restrict__ a_src,
                              const float* __restrict__ a_dst, float* __restrict__ as_out,
                              float* __restrict__ ad_out, int N, int H) {
  int wave = threadIdx.x >> 6, lane = threadIdx.x & 63;
  int n = blockIdx.x * 4 + wave;
  if (n >= N) return;
  const float* row = hmat + (size_t)n * H * 64;
  for (int h = 0; h < H; ++h) {
    float v = row[h * 64 + lane];
    float ps = v * a_src[h * 64 + lane];
    float pd = v * a_dst[h * 64 + lane];
#pragma unroll
    for (int off = 32; off; off >>= 1) {
      ps += __shfl_xor(ps, off);
      pd += __shfl_xor(pd, off);
    }
    if (lane == 0) {
      as_out[(size_t)n * H + h] = ps;
      ad_out[(size_t)n * H + h] = pd;
    }
  }
}

__device__ __forceinline__ float lrelu(float e) { return e > 0.f ? e : NEG_SLOPE * e; }

// ---------------- per-edge logits (leaky_relu applied), H=4 ----------------
__global__ void logits1_kernel(const int* __restrict__ srcs, const int* __restrict__ dsts,
                               const float* __restrict__ as1, const float* __restrict__ ad1,
                               float* __restrict__ e1, int Etot) {
  int j = blockIdx.x * blockDim.x + threadIdx.x;
  if (j >= Etot) return;
  int s = srcs[j], d = dsts[j];
  float4 a = *reinterpret_cast<const float4*>(&as1[(size_t)s * 4]);
  float4 b = *reinterpret_cast<const float4*>(&ad1[(size_t)d * 4]);
  float4 e;
  e.x = lrelu(a.x + b.x); e.y = lrelu(a.y + b.y);
  e.z = lrelu(a.z + b.z); e.w = lrelu(a.w + b.w);
  *reinterpret_cast<float4*>(&e1[(size_t)j * 4]) = e;
}

// ---------------- per-edge logits, H=1 ----------------
__global__ void logits2_kernel(const int* __restrict__ srcs, const int* __restrict__ dsts,
                               const float* __restrict__ as2, const float* __restrict__ ad2,
                               float* __restrict__ e2, int Etot) {
  int j = blockIdx.x * blockDim.x + threadIdx.x;
  if (j >= Etot) return;
  e2[j] = lrelu(as2[srcs[j]] + ad2[dsts[j]]);
}

// ---------------- segment max + sum, H=4: thread per (node, head) ----------------
__global__ void maxsum1_kernel(const int* __restrict__ rowptr, const float* __restrict__ e1,
                               float* __restrict__ m1, float* __restrict__ rs1, int N) {
  int gid = blockIdx.x * blockDim.x + threadIdx.x;
  if (gid >= N * 4) return;
  int n = gid >> 2, h = gid & 3;
  int beg = rowptr[n], end = rowptr[n + 1];
  float m = -1e30f;
  for (int j = beg; j < end; ++j) m = fmaxf(m, e1[(size_t)j * 4 + h]);
  float s = 0.f;
  for (int j = beg; j < end; ++j) s += __expf(e1[(size_t)j * 4 + h] - m);
  m1[gid] = m;
  rs1[gid] = 1.f / (s + SM_EPS);
}

// ---------------- segment max + sum, H=1 ----------------
__global__ void maxsum2_kernel(const int* __restrict__ rowptr, const float* __restrict__ e2,
                               float* __restrict__ m2, float* __restrict__ rs2, int N) {
  int n = blockIdx.x * blockDim.x + threadIdx.x;
  if (n >= N) return;
  int beg = rowptr[n], end = rowptr[n + 1];
  float m = -1e30f;
  for (int j = beg; j < end; ++j) m = fmaxf(m, e2[j]);
  float s = 0.f;
  for (int j = beg; j < end; ++j) s += __expf(e2[j] - m);
  m2[n] = m;
  rs2[n] = 1.f / (s + SM_EPS);
}

// ---------------- layer-1 gather: wave per node, lane holds float4 (4 channels) ----
// fuses +b1 and ELU
__global__ __launch_bounds__(256) void gather1_kernel(const float* __restrict__ h1,
                                                      const int* __restrict__ rowptr,
                                                      const int* __restrict__ srcs,
                                                      const float* __restrict__ e1,
                                                      const float* __restrict__ m1,
                                                      const float* __restrict__ rs1,
                                                      const float* __restrict__ b1,
                                                      float* __restrict__ act1, int N) {
  const int wave = threadIdx.x >> 6, lane = threadIdx.x & 63;
  const int n = blockIdx.x * 4 + wave;
  if (n >= N) return;
  const int h = lane >> 4;  // head for this lane's 4 channels
  const int beg = rowptr[n], end = rowptr[n + 1];
  const float m = m1[(size_t)n * 4 + h];
  const float rs = rs1[(size_t)n * 4 + h];
  float4 acc = make_float4(0.f, 0.f, 0.f, 0.f);
  for (int j = beg; j < end; ++j) {
    int s = srcs[j];                                   // broadcast
    float w = __expf(e1[(size_t)j * 4 + h] - m) * rs;  // 4 distinct dwords/wave
    float4 v = *reinterpret_cast<const float4*>(&h1[(size_t)s * 256 + lane * 4]);
    acc.x = fmaf(w, v.x, acc.x); acc.y = fmaf(w, v.y, acc.y);
    acc.z = fmaf(w, v.z, acc.z); acc.w = fmaf(w, v.w, acc.w);
  }
  float4 bb = *reinterpret_cast<const float4*>(&b1[lane * 4]);
  float4 o;
  o.x = acc.x + bb.x; o.y = acc.y + bb.y; o.z = acc.z + bb.z; o.w = acc.w + bb.w;
  o.x = o.x > 0.f ? o.x : __expf(o.x) - 1.f;
  o.y = o.y > 0.f ? o.y : __expf(o.y) - 1.f;
  o.z = o.z > 0.f ? o.z : __expf(o.z) - 1.f;
  o.w = o.w > 0.f ? o.w : __expf(o.w) - 1.f;
  *reinterpret_cast<float4*>(&act1[(size_t)n * 256 + lane * 4]) = o;
}

// ---------------- layer-2 gather: wave per node, 4 edges x 16 lanes x float4 ----
// fuses +b2
__global__ __launch_bounds__(256) void gather2_kernel(const float* __restrict__ h2,
                                                      const int* __restrict__ rowptr,
                                                      const int* __restrict__ srcs,
                                                      const float* __restrict__ e2,
                                                      const float* __restrict__ m2,
                                                      const float* __restrict__ rs2,
                                                      const float* __restrict__ b2,
                                                      float* __restrict__ out, int N) {
  const int wave = threadIdx.x >> 6, lane = threadIdx.x & 63;
  const int n = blockIdx.x * 4 + wave;
  if (n >= N) return;
  const int g = lane >> 4;          // edge sub-group 0..3
  const int c4 = (lane & 15) * 4;   // channel base 0..60
  const int beg = rowptr[n], end = rowptr[n + 1];
  const float m = m2[n], rs = rs2[n];
  float4 acc = make_float4(0.f, 0.f, 0.f, 0.f);
  for (int j0 = beg; j0 < end; j0 += 4) {
    int j = j0 + g;
    float w = 0.f;
    int s = 0;
    if (j < end) {
      s = srcs[j];
      w = __expf(e2[j] - m) * rs;
    }
    float4 v = *reinterpret_cast<const float4*>(&h2[(size_t)s * 64 + c4]);
    acc.x = fmaf(w, v.x, acc.x); acc.y = fmaf(w, v.y, acc.y);
    acc.z = fmaf(w, v.z, acc.z); acc.w = fmaf(w, v.w, acc.w);
  }
#pragma unroll
  for (int off = 16; off <= 32; off <<= 1) {
    acc.x += __shfl_xor(acc.x, off);
    acc.y += __shfl_xor(acc.y, off);
    acc.z += __shfl_xor(acc.z, off);
    acc.w += __shfl_xor(acc.w, off);
  }
  if (lane < 16) {
    float4 bb = *reinterpret_cast<const float4*>(&b2[c4]);
    float4 o = make_float4(acc.x + bb.x, acc.y + bb.y, acc.z + bb.z, acc.w + bb.w);
    *reinterpret_cast<float4*>(&out[(size_t)n * 64 + c4]) = o;
  }
}

extern "C" void kernel_launch(void* const* d_in, const int* in_sizes, int n_in,
                              void* d_out, int out_size, void* d_ws, size_t ws_size,
                              hipStream_t stream) {
  const float* x      = (const float*)d_in[0];
  const int*   ei     = (const int*)d_in[1];
  const float* W1     = (const float*)d_in[2];
  const float* a_src1 = (const float*)d_in[3];
  const float* a_dst1 = (const float*)d_in[4];
  const float* b1     = (const float*)d_in[5];
  const float* W2     = (const float*)d_in[6];
  const float* a_src2 = (const float*)d_in[7];
  const float* a_dst2 = (const float*)d_in[8];
  const float* b2     = (const float*)d_in[9];
  float* out = (float*)d_out;

  const int N = in_sizes[0] / 256;  // 50000
  const int E = in_sizes[1] / 2;    // 800000
  const int Etot = E + N;
  const int K = 256;

  char* ws = (char*)d_ws;
  size_t off = 0;
  auto alloc = [&](size_t bytes) -> void* {
    off = (off + 255) & ~(size_t)255;
    void* p = ws + off;
    off += bytes;
    return p;
  };
  float* h1     = (float*)alloc((size_t)N * 256 * 4);  // reused as h2 (N*64) in L2
  float* act1   = (float*)alloc((size_t)N * 256 * 4);
  float* as1    = (float*)alloc((size_t)N * 4 * 4);
  float* ad1    = (float*)alloc((size_t)N * 4 * 4);
  float* m1     = (float*)alloc((size_t)N * 4 * 4);
  float* rs1    = (float*)alloc((size_t)N * 4 * 4);
  float* e1     = (float*)alloc((size_t)Etot * 4 * 4);
  int*   counts = (int*)alloc((size_t)N * 4);
  int*   rowptr = (int*)alloc((size_t)(N + 1) * 4);
  int*   cursor = (int*)alloc((size_t)N * 4);
  int*   srcs   = (int*)alloc((size_t)Etot * 4);
  int*   dsts   = (int*)alloc((size_t)Etot * 4);
  // layer-2 aliases (layer-1 buffers dead by then)
  float* as2 = as1;
  float* ad2 = ad1;
  float* m2  = m1;
  float* rs2 = rs1;
  float* e2  = e1;
  (void)ws_size; (void)n_in; (void)out_size;

  // CSR build
  hipMemsetAsync(counts, 0, (size_t)N * 4, stream);
  int eblocks = (Etot + 255) / 256;
  count_kernel<<<eblocks, 256, 0, stream>>>(ei, E, N, counts);
  scan_kernel<<<1, 1024, 0, stream>>>(counts, rowptr, cursor, N);
  scatter_kernel<<<eblocks, 256, 0, stream>>>(ei, E, N, cursor, srcs, dsts);

  // Layer 1
  {
    dim3 grid((N + 63) / 64, 256 / 64);
    gemm_abT<<<grid, 256, 0, stream>>>(x, W1, h1, N, 256, K);
  }
  alphas_kernel<<<(N + 3) / 4, 256, 0, stream>>>(h1, a_src1, a_dst1, as1, ad1, N, 4);
  logits1_kernel<<<eblocks, 256, 0, stream>>>(srcs, dsts, as1, ad1, e1, Etot);
  maxsum1_kernel<<<(N * 4 + 255) / 256, 256, 0, stream>>>(rowptr, e1, m1, rs1, N);
  gather1_kernel<<<(N + 3) / 4, 256, 0, stream>>>(h1, rowptr, srcs, e1, m1, rs1, b1, act1, N);

  // Layer 2 (h2 aliases h1)
  float* h2 = h1;
  {
    dim3 grid((N + 63) / 64, 64 / 64);
    gemm_abT<<<grid, 256, 0, stream>>>(act1, W2, h2, N, 64, K);
  }
  alphas_kernel<<<(N + 3) / 4, 256, 0, stream>>>(h2, a_src2, a_dst2, as2, ad2, N, 1);
  logits2_kernel<<<eblocks, 256, 0, stream>>>(srcs, dsts, as2, ad2, e2, Etot);
  maxsum2_kernel<<<(N + 255) / 256, 256, 0, stream>>>(rowptr, e2, m2, rs2, N);
  gather2_kernel<<<(N + 3) / 4, 256, 0, stream>>>(h2, rowptr, srcs, e2, m2, rs2, b2, out, N);
}

// Round 3
// 379.463 us; speedup vs baseline: 2.4492x; 1.4268x over previous
//
#include <hip/hip_runtime.h>
#include <hip/hip_bf16.h>

// GAT encoder, 2 layers. L1: h1=x@W1^T (N,4,64) [stored bf16], softmax-attn
// aggregate + b1 + ELU -> act1 (N,256) fp32. L2: h2=act1@W2^T (N,64) fp32,
// attn, out = aggregate + b2.
// N=50000, E=800000 (+N self-loops), IN=256, H1=4, D=64, OUT=64.

#define NEG_SLOPE 0.2f
#define SM_EPS 1e-16f

typedef unsigned short u16;
typedef unsigned int u32;

__device__ __forceinline__ float bf2f(u16 u) { return __uint_as_float(((u32)u) << 16); }
__device__ __forceinline__ u16 f2bf(float f) {
  u32 u = __float_as_uint(f);
  u = (u + 0x7FFFu + ((u >> 16) & 1u)) >> 16;
  return (u16)u;
}
__device__ __forceinline__ float lrelu(float e) { return e > 0.f ? e : NEG_SLOPE * e; }

// ---------------- GEMM: C[M,Ncols] = A[M,K] @ B[Ncols,K]^T ----------------
// BM=64, BN=64, BK=32, 256 threads, 4x4 per-thread tile. OUTBF16 selects C dtype.
template <int OUTBF16>
__global__ __launch_bounds__(256) void gemm_abT(const float* __restrict__ A,
                                                const float* __restrict__ B,
                                                void* __restrict__ Cv,
                                                int M, int Ncols, int K) {
  __shared__ float As[32][68];
  __shared__ float Bs[32][68];
  const int t = threadIdx.x;
  const int tm = t >> 4, tn = t & 15;
  const int row0 = blockIdx.x * 64, col0 = blockIdx.y * 64;
  float acc[4][4] = {};
  for (int k0 = 0; k0 < K; k0 += 32) {
#pragma unroll
    for (int i = 0; i < 2; ++i) {
      int lid = t + i * 256;
      int ar = lid >> 3;
      int ac = (lid & 7) << 2;
      float4 v = make_float4(0.f, 0.f, 0.f, 0.f);
      int gr = row0 + ar;
      if (gr < M) v = *reinterpret_cast<const float4*>(&A[(size_t)gr * K + k0 + ac]);
      As[ac + 0][ar] = v.x; As[ac + 1][ar] = v.y; As[ac + 2][ar] = v.z; As[ac + 3][ar] = v.w;
      float4 w = *reinterpret_cast<const float4*>(&B[(size_t)(col0 + ar) * K + k0 + ac]);
      Bs[ac + 0][ar] = w.x; Bs[ac + 1][ar] = w.y; Bs[ac + 2][ar] = w.z; Bs[ac + 3][ar] = w.w;
    }
    __syncthreads();
#pragma unroll
    for (int k = 0; k < 32; ++k) {
      float4 a = *reinterpret_cast<const float4*>(&As[k][tm * 4]);
      float4 b = *reinterpret_cast<const float4*>(&Bs[k][tn * 4]);
      acc[0][0] = fmaf(a.x, b.x, acc[0][0]); acc[0][1] = fmaf(a.x, b.y, acc[0][1]);
      acc[0][2] = fmaf(a.x, b.z, acc[0][2]); acc[0][3] = fmaf(a.x, b.w, acc[0][3]);
      acc[1][0] = fmaf(a.y, b.x, acc[1][0]); acc[1][1] = fmaf(a.y, b.y, acc[1][1]);
      acc[1][2] = fmaf(a.y, b.z, acc[1][2]); acc[1][3] = fmaf(a.y, b.w, acc[1][3]);
      acc[2][0] = fmaf(a.z, b.x, acc[2][0]); acc[2][1] = fmaf(a.z, b.y, acc[2][1]);
      acc[2][2] = fmaf(a.z, b.z, acc[2][2]); acc[2][3] = fmaf(a.z, b.w, acc[2][3]);
      acc[3][0] = fmaf(a.w, b.x, acc[3][0]); acc[3][1] = fmaf(a.w, b.y, acc[3][1]);
      acc[3][2] = fmaf(a.w, b.z, acc[3][2]); acc[3][3] = fmaf(a.w, b.w, acc[3][3]);
    }
    __syncthreads();
  }
#pragma unroll
  for (int i = 0; i < 4; ++i) {
    int r = row0 + tm * 4 + i;
    if (r < M) {
      if (OUTBF16) {
        u16* C = (u16*)Cv;
        ushort4 v;
        v.x = f2bf(acc[i][0]); v.y = f2bf(acc[i][1]);
        v.z = f2bf(acc[i][2]); v.w = f2bf(acc[i][3]);
        *reinterpret_cast<ushort4*>(&C[(size_t)r * Ncols + col0 + tn * 4]) = v;
      } else {
        float* C = (float*)Cv;
        float4 v = make_float4(acc[i][0], acc[i][1], acc[i][2], acc[i][3]);
        *reinterpret_cast<float4*>(&C[(size_t)r * Ncols + col0 + tn * 4]) = v;
      }
    }
  }
}

// ---------------- CSR build ----------------
__global__ void count_kernel(const int* __restrict__ ei, int E, int N, int* __restrict__ counts) {
  int e = blockIdx.x * blockDim.x + threadIdx.x;
  if (e >= E + N) return;
  int d = (e < E) ? ei[E + e] : (e - E);
  atomicAdd(&counts[d], 1);
}

// hierarchical exclusive scan of counts[N] -> rowptr[N+1], cursor[N]
// s1: per-block (1024 elems) sums
__global__ __launch_bounds__(256) void blocksum_kernel(const int* __restrict__ counts,
                                                       int* __restrict__ bsums, int N) {
  const int b = blockIdx.x, t = threadIdx.x;
  const int base = b * 1024 + t * 4;
  int s = 0;
#pragma unroll
  for (int i = 0; i < 4; ++i) {
    int idx = base + i;
    if (idx < N) s += counts[idx];
  }
#pragma unroll
  for (int off = 1; off < 64; off <<= 1) s += __shfl_xor(s, off);
  __shared__ int ws[4];
  if ((t & 63) == 0) ws[t >> 6] = s;
  __syncthreads();
  if (t == 0) bsums[b] = ws[0] + ws[1] + ws[2] + ws[3];
}

// s2: single-wave in-place exclusive scan of bsums[nb]
__global__ void scanbsums_kernel(int* __restrict__ bsums, int nb) {
  const int t = threadIdx.x;  // 64
  int carry = 0;
  for (int base = 0; base < nb; base += 64) {
    int i = base + t;
    int orig = (i < nb) ? bsums[i] : 0;
    int v = orig;
#pragma unroll
    for (int off = 1; off < 64; off <<= 1) {
      int u = __shfl_up(v, off);
      if (t >= off) v += u;
    }
    if (i < nb) bsums[i] = carry + v - orig;
    carry += __shfl(v, 63);
  }
}

// s3: per-block rescan + write rowptr/cursor
__global__ __launch_bounds__(256) void scanfinal_kernel(const int* __restrict__ counts,
                                                        const int* __restrict__ boffs,
                                                        int* __restrict__ rowptr,
                                                        int* __restrict__ cursor, int N) {
  const int b = blockIdx.x, t = threadIdx.x;
  const int wave = t >> 6, lane = t & 63;
  const int base = b * 1024 + t * 4;
  int v[4];
#pragma unroll
  for (int i = 0; i < 4; ++i) {
    int idx = base + i;
    v[i] = (idx < N) ? counts[idx] : 0;
  }
  int ts = v[0] + v[1] + v[2] + v[3];
  int inc = ts;
#pragma unroll
  for (int off = 1; off < 64; off <<= 1) {
    int u = __shfl_up(inc, off);
    if (lane >= off) inc += u;
  }
  __shared__ int wsum[4];
  if (lane == 63) wsum[wave] = inc;
  __syncthreads();
  int woff = 0;
  for (int w = 0; w < 4; ++w)
    if (w < wave) woff += wsum[w];
  int run = boffs[b] + woff + (inc - ts);
#pragma unroll
  for (int i = 0; i < 4; ++i) {
    int idx = base + i;
    if (idx < N) {
      rowptr[idx] = run;
      cursor[idx] = run;
    }
    run += v[i];
  }
  if (N - 1 >= base && N - 1 < base + 4) rowptr[N] = run;  // run == total prefix through N-1
}

__global__ void scatter_kernel(const int* __restrict__ ei, int E, int N,
                               int* __restrict__ cursor, int* __restrict__ srcs,
                               int* __restrict__ dsts) {
  int e = blockIdx.x * blockDim.x + threadIdx.x;
  if (e >= E + N) return;
  int s = (e < E) ? ei[e] : (e - E);
  int d = (e < E) ? ei[E + e] : (e - E);
  int pos = atomicAdd(&cursor[d], 1);
  srcs[pos] = s;
  dsts[pos] = d;
}

// ---------------- attention logits per node, layer 1 (bf16 h1, H=4) ----------------
__global__ void alphas1_kernel(const u16* __restrict__ h1b, const float* __restrict__ a_src,
                               const float* __restrict__ a_dst, float* __restrict__ as1,
                               float* __restrict__ ad1, int N) {
  const int wave = threadIdx.x >> 6, lane = threadIdx.x & 63;
  const int n = blockIdx.x * 4 + wave;
  if (n >= N) return;
  ushort4 v = *reinterpret_cast<const ushort4*>(&h1b[(size_t)n * 256 + lane * 4]);
  float4 a = *reinterpret_cast<const float4*>(&a_src[lane * 4]);
  float4 d = *reinterpret_cast<const float4*>(&a_dst[lane * 4]);
  float f0 = bf2f(v.x), f1 = bf2f(v.y), f2 = bf2f(v.z), f3 = bf2f(v.w);
  float ps = f0 * a.x + f1 * a.y + f2 * a.z + f3 * a.w;
  float pd = f0 * d.x + f1 * d.y + f2 * d.z + f3 * d.w;
#pragma unroll
  for (int off = 1; off < 16; off <<= 1) {
    ps += __shfl_xor(ps, off);
    pd += __shfl_xor(pd, off);
  }
  if ((lane & 15) == 0) {
    as1[(size_t)n * 4 + (lane >> 4)] = ps;
    ad1[(size_t)n * 4 + (lane >> 4)] = pd;
  }
}

// ---------------- attention logits, layer 2 (fp32 h2, H=1) ----------------
__global__ void alphas2_kernel(const float* __restrict__ h2, const float* __restrict__ a_src,
                               const float* __restrict__ a_dst, float* __restrict__ as2,
                               float* __restrict__ ad2, int N) {
  const int wave = threadIdx.x >> 6, lane = threadIdx.x & 63;
  const int n = blockIdx.x * 4 + wave;
  if (n >= N) return;
  float v = h2[(size_t)n * 64 + lane];
  float ps = v * a_src[lane];
  float pd = v * a_dst[lane];
#pragma unroll
  for (int off = 32; off; off >>= 1) {
    ps += __shfl_xor(ps, off);
    pd += __shfl_xor(pd, off);
  }
  if (lane == 0) {
    as2[n] = ps;
    ad2[n] = pd;
  }
}

// ---------------- per-edge logits (leaky_relu applied), H=4 ----------------
__global__ void logits1_kernel(const int* __restrict__ srcs, const int* __restrict__ dsts,
                               const float* __restrict__ as1, const float* __restrict__ ad1,
                               float* __restrict__ e1, int Etot) {
  int j = blockIdx.x * blockDim.x + threadIdx.x;
  if (j >= Etot) return;
  int s = srcs[j], d = dsts[j];
  float4 a = *reinterpret_cast<const float4*>(&as1[(size_t)s * 4]);
  float4 b = *reinterpret_cast<const float4*>(&ad1[(size_t)d * 4]);
  float4 e;
  e.x = lrelu(a.x + b.x); e.y = lrelu(a.y + b.y);
  e.z = lrelu(a.z + b.z); e.w = lrelu(a.w + b.w);
  *reinterpret_cast<float4*>(&e1[(size_t)j * 4]) = e;
}

__global__ void logits2_kernel(const int* __restrict__ srcs, const int* __restrict__ dsts,
                               const float* __restrict__ as2, const float* __restrict__ ad2,
                               float* __restrict__ e2, int Etot) {
  int j = blockIdx.x * blockDim.x + threadIdx.x;
  if (j >= Etot) return;
  e2[j] = lrelu(as2[srcs[j]] + ad2[dsts[j]]);
}

// ---------------- segment max + sum ----------------
__global__ void maxsum1_kernel(const int* __restrict__ rowptr, const float* __restrict__ e1,
                               float* __restrict__ m1, float* __restrict__ rs1, int N) {
  int gid = blockIdx.x * blockDim.x + threadIdx.x;
  if (gid >= N * 4) return;
  int n = gid >> 2, h = gid & 3;
  int beg = rowptr[n], end = rowptr[n + 1];
  float m = -1e30f;
  for (int j = beg; j < end; ++j) m = fmaxf(m, e1[(size_t)j * 4 + h]);
  float s = 0.f;
  for (int j = beg; j < end; ++j) s += __expf(e1[(size_t)j * 4 + h] - m);
  m1[gid] = m;
  rs1[gid] = 1.f / (s + SM_EPS);
}

__global__ void maxsum2_kernel(const int* __restrict__ rowptr, const float* __restrict__ e2,
                               float* __restrict__ m2, float* __restrict__ rs2, int N) {
  int n = blockIdx.x * blockDim.x + threadIdx.x;
  if (n >= N) return;
  int beg = rowptr[n], end = rowptr[n + 1];
  float m = -1e30f;
  for (int j = beg; j < end; ++j) m = fmaxf(m, e2[j]);
  float s = 0.f;
  for (int j = beg; j < end; ++j) s += __expf(e2[j] - m);
  m2[n] = m;
  rs2[n] = 1.f / (s + SM_EPS);
}

// ---------------- layer-1 gather (bf16 h1): wave per node, lane holds 4 channels ----
// fuses +b1 and ELU; 2-edge unroll for MLP.
__global__ __launch_bounds__(256) void gather1_kernel(const u16* __restrict__ h1b,
                                                      const int* __restrict__ rowptr,
                                                      const int* __restrict__ srcs,
                                                      const float* __restrict__ e1,
                                                      const float* __restrict__ m1,
                                                      const float* __restrict__ rs1,
                                                      const float* __restrict__ b1,
                                                      float* __restrict__ act1, int N) {
  const int wave = threadIdx.x >> 6, lane = threadIdx.x & 63;
  const int n = blockIdx.x * 4 + wave;
  if (n >= N) return;
  const int h = lane >> 4;
  const int beg = rowptr[n], end = rowptr[n + 1];
  const float m = m1[(size_t)n * 4 + h];
  const float rs = rs1[(size_t)n * 4 + h];
  float4 acc = make_float4(0.f, 0.f, 0.f, 0.f);
  int j = beg;
  for (; j + 1 < end; j += 2) {
    int s0 = srcs[j], s1 = srcs[j + 1];
    float w0 = __expf(e1[(size_t)j * 4 + h] - m) * rs;
    float w1 = __expf(e1[(size_t)(j + 1) * 4 + h] - m) * rs;
    ushort4 v0 = *reinterpret_cast<const ushort4*>(&h1b[(size_t)s0 * 256 + lane * 4]);
    ushort4 v1 = *reinterpret_cast<const ushort4*>(&h1b[(size_t)s1 * 256 + lane * 4]);
    acc.x = fmaf(w0, bf2f(v0.x), acc.x); acc.y = fmaf(w0, bf2f(v0.y), acc.y);
    acc.z = fmaf(w0, bf2f(v0.z), acc.z); acc.w = fmaf(w0, bf2f(v0.w), acc.w);
    acc.x = fmaf(w1, bf2f(v1.x), acc.x); acc.y = fmaf(w1, bf2f(v1.y), acc.y);
    acc.z = fmaf(w1, bf2f(v1.z), acc.z); acc.w = fmaf(w1, bf2f(v1.w), acc.w);
  }
  if (j < end) {
    int s0 = srcs[j];
    float w0 = __expf(e1[(size_t)j * 4 + h] - m) * rs;
    ushort4 v0 = *reinterpret_cast<const ushort4*>(&h1b[(size_t)s0 * 256 + lane * 4]);
    acc.x = fmaf(w0, bf2f(v0.x), acc.x); acc.y = fmaf(w0, bf2f(v0.y), acc.y);
    acc.z = fmaf(w0, bf2f(v0.z), acc.z); acc.w = fmaf(w0, bf2f(v0.w), acc.w);
  }
  float4 bb = *reinterpret_cast<const float4*>(&b1[lane * 4]);
  float4 o;
  o.x = acc.x + bb.x; o.y = acc.y + bb.y; o.z = acc.z + bb.z; o.w = acc.w + bb.w;
  o.x = o.x > 0.f ? o.x : __expf(o.x) - 1.f;
  o.y = o.y > 0.f ? o.y : __expf(o.y) - 1.f;
  o.z = o.z > 0.f ? o.z : __expf(o.z) - 1.f;
  o.w = o.w > 0.f ? o.w : __expf(o.w) - 1.f;
  *reinterpret_cast<float4*>(&act1[(size_t)n * 256 + lane * 4]) = o;
}

// ---------------- layer-2 gather: wave per node, 4 edges x 16 lanes x float4 ----
__global__ __launch_bounds__(256) void gather2_kernel(const float* __restrict__ h2,
                                                      const int* __restrict__ rowptr,
                                                      const int* __restrict__ srcs,
                                                      const float* __restrict__ e2,
                                                      const float* __restrict__ m2,
                                                      const float* __restrict__ rs2,
                                                      const float* __restrict__ b2,
                                                      float* __restrict__ out, int N) {
  const int wave = threadIdx.x >> 6, lane = threadIdx.x & 63;
  const int n = blockIdx.x * 4 + wave;
  if (n >= N) return;
  const int g = lane >> 4;
  const int c4 = (lane & 15) * 4;
  const int beg = rowptr[n], end = rowptr[n + 1];
  const float m = m2[n], rs = rs2[n];
  float4 acc = make_float4(0.f, 0.f, 0.f, 0.f);
  for (int j0 = beg; j0 < end; j0 += 4) {
    int j = j0 + g;
    float w = 0.f;
    int s = 0;
    if (j < end) {
      s = srcs[j];
      w = __expf(e2[j] - m) * rs;
    }
    float4 v = *reinterpret_cast<const float4*>(&h2[(size_t)s * 64 + c4]);
    acc.x = fmaf(w, v.x, acc.x); acc.y = fmaf(w, v.y, acc.y);
    acc.z = fmaf(w, v.z, acc.z); acc.w = fmaf(w, v.w, acc.w);
  }
#pragma unroll
  for (int off = 16; off <= 32; off <<= 1) {
    acc.x += __shfl_xor(acc.x, off);
    acc.y += __shfl_xor(acc.y, off);
    acc.z += __shfl_xor(acc.z, off);
    acc.w += __shfl_xor(acc.w, off);
  }
  if (lane < 16) {
    float4 bb = *reinterpret_cast<const float4*>(&b2[c4]);
    float4 o = make_float4(acc.x + bb.x, acc.y + bb.y, acc.z + bb.z, acc.w + bb.w);
    *reinterpret_cast<float4*>(&out[(size_t)n * 64 + c4]) = o;
  }
}

extern "C" void kernel_launch(void* const* d_in, const int* in_sizes, int n_in,
                              void* d_out, int out_size, void* d_ws, size_t ws_size,
                              hipStream_t stream) {
  const float* x      = (const float*)d_in[0];
  const int*   ei     = (const int*)d_in[1];
  const float* W1     = (const float*)d_in[2];
  const float* a_src1 = (const float*)d_in[3];
  const float* a_dst1 = (const float*)d_in[4];
  const float* b1     = (const float*)d_in[5];
  const float* W2     = (const float*)d_in[6];
  const float* a_src2 = (const float*)d_in[7];
  const float* a_dst2 = (const float*)d_in[8];
  const float* b2     = (const float*)d_in[9];
  float* out = (float*)d_out;

  const int N = in_sizes[0] / 256;  // 50000
  const int E = in_sizes[1] / 2;    // 800000
  const int Etot = E + N;
  const int K = 256;

  char* ws = (char*)d_ws;
  size_t off = 0;
  auto alloc = [&](size_t bytes) -> void* {
    off = (off + 255) & ~(size_t)255;
    void* p = ws + off;
    off += bytes;
    return p;
  };
  u16*   h1b    = (u16*)alloc((size_t)N * 256 * 2);    // bf16 h1
  float* act1   = (float*)alloc((size_t)N * 256 * 4);
  float* h2     = (float*)alloc((size_t)N * 64 * 4);
  float* as1    = (float*)alloc((size_t)N * 4 * 4);
  float* ad1    = (float*)alloc((size_t)N * 4 * 4);
  float* m1     = (float*)alloc((size_t)N * 4 * 4);
  float* rs1    = (float*)alloc((size_t)N * 4 * 4);
  float* e1     = (float*)alloc((size_t)Etot * 4 * 4);
  int*   counts = (int*)alloc((size_t)N * 4);
  int*   rowptr = (int*)alloc((size_t)(N + 1) * 4);
  int*   cursor = (int*)alloc((size_t)N * 4);
  int*   srcs   = (int*)alloc((size_t)Etot * 4);
  int*   dsts   = (int*)alloc((size_t)Etot * 4);
  int*   bsums  = (int*)alloc((size_t)256 * 4);
  // layer-2 aliases (layer-1 versions dead by then)
  float* as2 = as1;
  float* ad2 = ad1;
  float* m2  = m1;
  float* rs2 = rs1;
  float* e2  = e1;
  (void)ws_size; (void)n_in; (void)out_size;

  // CSR build
  hipMemsetAsync(counts, 0, (size_t)N * 4, stream);
  int eblocks = (Etot + 255) / 256;
  count_kernel<<<eblocks, 256, 0, stream>>>(ei, E, N, counts);
  const int nb = (N + 1023) / 1024;
  blocksum_kernel<<<nb, 256, 0, stream>>>(counts, bsums, N);
  scanbsums_kernel<<<1, 64, 0, stream>>>(bsums, nb);
  scanfinal_kernel<<<nb, 256, 0, stream>>>(counts, bsums, rowptr, cursor, N);
  scatter_kernel<<<eblocks, 256, 0, stream>>>(ei, E, N, cursor, srcs, dsts);

  // Layer 1
  {
    dim3 grid((N + 63) / 64, 256 / 64);
    gemm_abT<1><<<grid, 256, 0, stream>>>(x, W1, (void*)h1b, N, 256, K);
  }
  alphas1_kernel<<<(N + 3) / 4, 256, 0, stream>>>(h1b, a_src1, a_dst1, as1, ad1, N);
  logits1_kernel<<<eblocks, 256, 0, stream>>>(srcs, dsts, as1, ad1, e1, Etot);
  maxsum1_kernel<<<(N * 4 + 255) / 256, 256, 0, stream>>>(rowptr, e1, m1, rs1, N);
  gather1_kernel<<<(N + 3) / 4, 256, 0, stream>>>(h1b, rowptr, srcs, e1, m1, rs1, b1, act1, N);

  // Layer 2
  {
    dim3 grid((N + 63) / 64, 64 / 64);
    gemm_abT<0><<<grid, 256, 0, stream>>>(act1, W2, (void*)h2, N, 64, K);
  }
  alphas2_kernel<<<(N + 3) / 4, 256, 0, stream>>>(h2, a_src2, a_dst2, as2, ad2, N);
  logits2_kernel<<<eblocks, 256, 0, stream>>>(srcs, dsts, as2, ad2, e2, Etot);
  maxsum2_kernel<<<(N + 255) / 256, 256, 0, stream>>>(rowptr, e2, m2, rs2, N);
  gather2_kernel<<<(N + 3) / 4, 256, 0, stream>>>(h2, rowptr, srcs, e2, m2, rs2, b2, out, N);
}

// Round 4
// 303.578 us; speedup vs baseline: 3.0614x; 1.2500x over previous
//
#include <hip/hip_runtime.h>
#include <hip/hip_bf16.h>

// GAT encoder, 2 layers, MFMA GEMMs.
// L1: h1=x@W1^T (N,4,64) bf16; attn softmax; act1=ELU(agg+b1) bf16 (N,256).
// L2: h2=act1@W2^T (N,64) bf16; attn; out=agg+b2 fp32 (N,64).
// N=50000, E=800000 (+N self-loops), K=256.

#define NEG_SLOPE 0.2f
#define SM_EPS 1e-16f

typedef unsigned short u16;
typedef unsigned int u32;
typedef __attribute__((ext_vector_type(8))) short short8v;
typedef __attribute__((ext_vector_type(4))) float f32x4;

__device__ __forceinline__ float bf2f(u16 u) { return __uint_as_float(((u32)u) << 16); }
__device__ __forceinline__ u16 f2bf(float f) {
  u32 u = __float_as_uint(f);
  u = (u + 0x7FFFu + ((u >> 16) & 1u)) >> 16;
  return (u16)u;
}
__device__ __forceinline__ float lrelu(float e) { return e > 0.f ? e : NEG_SLOPE * e; }

// ---------------- MFMA GEMM: C[M][BN] = A[M][256] @ B[BN][256]^T, C bf16 ----
// BM=64 rows/block, BK=128 (2 chunks), 4 waves in WGM x WGN grid.
// A: bf16 (ABF16=1) or fp32 (converted during staging). B: fp32.
// LDS tiles XOR-swizzled (short idx ^= (row&7)<<3) to balance frag-read banks.
template <int BN, int WGM, int WGN, int ABF16>
__global__ __launch_bounds__(256, 2) void gemm_mfma(const void* __restrict__ Av,
                                                    const float* __restrict__ B,
                                                    u16* __restrict__ C, int M) {
  constexpr int K = 256, BK = 128, BM = 64;
  constexpr int WM = BM / WGM, WN = BN / WGN;
  constexpr int MF = WM / 16, NF = WN / 16;
  __shared__ short lds[(BM + BN) * BK];
  short* Al = lds;
  short* Bl = lds + BM * BK;
  const int t = threadIdx.x;
  const int wid = t >> 6, lane = t & 63;
  const int wm = wid / WGN, wn = wid % WGN;
  const int row0 = blockIdx.x * BM;
  const int l15 = lane & 15, l4 = lane >> 4;
  f32x4 acc[MF][NF] = {};
  for (int k0 = 0; k0 < K; k0 += BK) {
    // stage A (64 rows x 128 k, 16B granules)
    for (int g = t; g < BM * 16; g += 256) {
      int row = g >> 4, c = g & 15;
      int gr = row0 + row;
      short8v v;
      if (ABF16) {
        if (gr < M)
          v = *reinterpret_cast<const short8v*>((const short*)Av + (size_t)gr * K + k0 + c * 8);
        else
          v = (short8v)(short)0;
      } else {
        if (gr < M) {
          const float* ap = (const float*)Av + (size_t)gr * K + k0 + c * 8;
          float4 f0 = *reinterpret_cast<const float4*>(ap);
          float4 f1 = *reinterpret_cast<const float4*>(ap + 4);
          v[0] = (short)f2bf(f0.x); v[1] = (short)f2bf(f0.y);
          v[2] = (short)f2bf(f0.z); v[3] = (short)f2bf(f0.w);
          v[4] = (short)f2bf(f1.x); v[5] = (short)f2bf(f1.y);
          v[6] = (short)f2bf(f1.z); v[7] = (short)f2bf(f1.w);
        } else {
          v = (short8v)(short)0;
        }
      }
      *reinterpret_cast<short8v*>(&Al[row * BK + ((c * 8) ^ ((row & 7) << 3))]) = v;
    }
    // stage B (BN rows x 128 k)
    for (int g = t; g < BN * 16; g += 256) {
      int row = g >> 4, c = g & 15;
      const float* bp = B + (size_t)row * K + k0 + c * 8;
      float4 f0 = *reinterpret_cast<const float4*>(bp);
      float4 f1 = *reinterpret_cast<const float4*>(bp + 4);
      short8v v;
      v[0] = (short)f2bf(f0.x); v[1] = (short)f2bf(f0.y);
      v[2] = (short)f2bf(f0.z); v[3] = (short)f2bf(f0.w);
      v[4] = (short)f2bf(f1.x); v[5] = (short)f2bf(f1.y);
      v[6] = (short)f2bf(f1.z); v[7] = (short)f2bf(f1.w);
      *reinterpret_cast<short8v*>(&Bl[row * BK + ((c * 8) ^ ((row & 7) << 3))]) = v;
    }
    __syncthreads();
#pragma unroll
    for (int ks = 0; ks < BK / 32; ++ks) {
      short8v af[MF], bfr[NF];
#pragma unroll
      for (int fm = 0; fm < MF; ++fm) {
        int row = wm * WM + fm * 16 + l15;
        int col = (ks * 32 + l4 * 8) ^ ((row & 7) << 3);
        af[fm] = *reinterpret_cast<const short8v*>(&Al[row * BK + col]);
      }
#pragma unroll
      for (int fn = 0; fn < NF; ++fn) {
        int row = wn * WN + fn * 16 + l15;
        int col = (ks * 32 + l4 * 8) ^ ((row & 7) << 3);
        bfr[fn] = *reinterpret_cast<const short8v*>(&Bl[row * BK + col]);
      }
#pragma unroll
      for (int fm = 0; fm < MF; ++fm)
#pragma unroll
        for (int fn = 0; fn < NF; ++fn)
          acc[fm][fn] =
              __builtin_amdgcn_mfma_f32_16x16x32_bf16(af[fm], bfr[fn], acc[fm][fn], 0, 0, 0);
    }
    __syncthreads();
  }
  // store C bf16: col=lane&15, row=(lane>>4)*4+r (m89-verified C/D layout)
#pragma unroll
  for (int fm = 0; fm < MF; ++fm) {
#pragma unroll
    for (int fn = 0; fn < NF; ++fn) {
      int r0 = row0 + wm * WM + fm * 16 + l4 * 4;
      int col = wn * WN + fn * 16 + l15;
#pragma unroll
      for (int r = 0; r < 4; ++r)
        if (r0 + r < M) C[(size_t)(r0 + r) * BN + col] = f2bf(acc[fm][fn][r]);
    }
  }
}

// ---------------- CSR build ----------------
__global__ void count_kernel(const int* __restrict__ ei, int E, int N, int* __restrict__ counts) {
  int e = blockIdx.x * blockDim.x + threadIdx.x;
  if (e >= E + N) return;
  int d = (e < E) ? ei[E + e] : (e - E);
  atomicAdd(&counts[d], 1);
}

__global__ __launch_bounds__(256) void blocksum_kernel(const int* __restrict__ counts,
                                                       int* __restrict__ bsums, int N) {
  const int b = blockIdx.x, t = threadIdx.x;
  const int base = b * 1024 + t * 4;
  int s = 0;
#pragma unroll
  for (int i = 0; i < 4; ++i) {
    int idx = base + i;
    if (idx < N) s += counts[idx];
  }
#pragma unroll
  for (int off = 1; off < 64; off <<= 1) s += __shfl_xor(s, off);
  __shared__ int ws[4];
  if ((t & 63) == 0) ws[t >> 6] = s;
  __syncthreads();
  if (t == 0) bsums[b] = ws[0] + ws[1] + ws[2] + ws[3];
}

__global__ void scanbsums_kernel(int* __restrict__ bsums, int nb) {
  const int t = threadIdx.x;  // 64
  int carry = 0;
  for (int base = 0; base < nb; base += 64) {
    int i = base + t;
    int orig = (i < nb) ? bsums[i] : 0;
    int v = orig;
#pragma unroll
    for (int off = 1; off < 64; off <<= 1) {
      int u = __shfl_up(v, off);
      if (t >= off) v += u;
    }
    if (i < nb) bsums[i] = carry + v - orig;
    carry += __shfl(v, 63);
  }
}

__global__ __launch_bounds__(256) void scanfinal_kernel(const int* __restrict__ counts,
                                                        const int* __restrict__ boffs,
                                                        int* __restrict__ rowptr,
                                                        int* __restrict__ cursor, int N) {
  const int b = blockIdx.x, t = threadIdx.x;
  const int wave = t >> 6, lane = t & 63;
  const int base = b * 1024 + t * 4;
  int v[4];
#pragma unroll
  for (int i = 0; i < 4; ++i) {
    int idx = base + i;
    v[i] = (idx < N) ? counts[idx] : 0;
  }
  int ts = v[0] + v[1] + v[2] + v[3];
  int inc = ts;
#pragma unroll
  for (int off = 1; off < 64; off <<= 1) {
    int u = __shfl_up(inc, off);
    if (lane >= off) inc += u;
  }
  __shared__ int wsum[4];
  if (lane == 63) wsum[wave] = inc;
  __syncthreads();
  int woff = 0;
  for (int w = 0; w < 4; ++w)
    if (w < wave) woff += wsum[w];
  int run = boffs[b] + woff + (inc - ts);
#pragma unroll
  for (int i = 0; i < 4; ++i) {
    int idx = base + i;
    if (idx < N) {
      rowptr[idx] = run;
      cursor[idx] = run;
    }
    run += v[i];
  }
  if (N - 1 >= base && N - 1 < base + 4) rowptr[N] = run;
}

__global__ void scatter_kernel(const int* __restrict__ ei, int E, int N,
                               int* __restrict__ cursor, int* __restrict__ srcs,
                               int* __restrict__ dsts) {
  int e = blockIdx.x * blockDim.x + threadIdx.x;
  if (e >= E + N) return;
  int s = (e < E) ? ei[e] : (e - E);
  int d = (e < E) ? ei[E + e] : (e - E);
  int pos = atomicAdd(&cursor[d], 1);
  srcs[pos] = s;
  dsts[pos] = d;
}

// ---------------- attention logits per node, layer 1 (bf16 h1, H=4) ----------------
__global__ void alphas1_kernel(const u16* __restrict__ h1b, const float* __restrict__ a_src,
                               const float* __restrict__ a_dst, float* __restrict__ as1,
                               float* __restrict__ ad1, int N) {
  const int wave = threadIdx.x >> 6, lane = threadIdx.x & 63;
  const int n = blockIdx.x * 4 + wave;
  if (n >= N) return;
  ushort4 v = *reinterpret_cast<const ushort4*>(&h1b[(size_t)n * 256 + lane * 4]);
  float4 a = *reinterpret_cast<const float4*>(&a_src[lane * 4]);
  float4 d = *reinterpret_cast<const float4*>(&a_dst[lane * 4]);
  float f0 = bf2f(v.x), f1 = bf2f(v.y), f2 = bf2f(v.z), f3 = bf2f(v.w);
  float ps = f0 * a.x + f1 * a.y + f2 * a.z + f3 * a.w;
  float pd = f0 * d.x + f1 * d.y + f2 * d.z + f3 * d.w;
#pragma unroll
  for (int off = 1; off < 16; off <<= 1) {
    ps += __shfl_xor(ps, off);
    pd += __shfl_xor(pd, off);
  }
  if ((lane & 15) == 0) {
    as1[(size_t)n * 4 + (lane >> 4)] = ps;
    ad1[(size_t)n * 4 + (lane >> 4)] = pd;
  }
}

// ---------------- attention logits, layer 2 (bf16 h2, H=1) ----------------
__global__ void alphas2_kernel(const u16* __restrict__ h2b, const float* __restrict__ a_src,
                               const float* __restrict__ a_dst, float* __restrict__ as2,
                               float* __restrict__ ad2, int N) {
  const int wave = threadIdx.x >> 6, lane = threadIdx.x & 63;
  const int n = blockIdx.x * 4 + wave;
  if (n >= N) return;
  float v = bf2f(h2b[(size_t)n * 64 + lane]);
  float ps = v * a_src[lane];
  float pd = v * a_dst[lane];
#pragma unroll
  for (int off = 32; off; off >>= 1) {
    ps += __shfl_xor(ps, off);
    pd += __shfl_xor(pd, off);
  }
  if (lane == 0) {
    as2[n] = ps;
    ad2[n] = pd;
  }
}

// ---------------- per-edge logits ----------------
__global__ void logits1_kernel(const int* __restrict__ srcs, const int* __restrict__ dsts,
                               const float* __restrict__ as1, const float* __restrict__ ad1,
                               float* __restrict__ e1, int Etot) {
  int j = blockIdx.x * blockDim.x + threadIdx.x;
  if (j >= Etot) return;
  int s = srcs[j], d = dsts[j];
  float4 a = *reinterpret_cast<const float4*>(&as1[(size_t)s * 4]);
  float4 b = *reinterpret_cast<const float4*>(&ad1[(size_t)d * 4]);
  float4 e;
  e.x = lrelu(a.x + b.x); e.y = lrelu(a.y + b.y);
  e.z = lrelu(a.z + b.z); e.w = lrelu(a.w + b.w);
  *reinterpret_cast<float4*>(&e1[(size_t)j * 4]) = e;
}

__global__ void logits2_kernel(const int* __restrict__ srcs, const int* __restrict__ dsts,
                               const float* __restrict__ as2, const float* __restrict__ ad2,
                               float* __restrict__ e2, int Etot) {
  int j = blockIdx.x * blockDim.x + threadIdx.x;
  if (j >= Etot) return;
  e2[j] = lrelu(as2[srcs[j]] + ad2[dsts[j]]);
}

// ---------------- segment max + sum ----------------
__global__ void maxsum1_kernel(const int* __restrict__ rowptr, const float* __restrict__ e1,
                               float* __restrict__ m1, float* __restrict__ rs1, int N) {
  int gid = blockIdx.x * blockDim.x + threadIdx.x;
  if (gid >= N * 4) return;
  int n = gid >> 2, h = gid & 3;
  int beg = rowptr[n], end = rowptr[n + 1];
  float m = -1e30f;
  for (int j = beg; j < end; ++j) m = fmaxf(m, e1[(size_t)j * 4 + h]);
  float s = 0.f;
  for (int j = beg; j < end; ++j) s += __expf(e1[(size_t)j * 4 + h] - m);
  m1[gid] = m;
  rs1[gid] = 1.f / (s + SM_EPS);
}

__global__ void maxsum2_kernel(const int* __restrict__ rowptr, const float* __restrict__ e2,
                               float* __restrict__ m2, float* __restrict__ rs2, int N) {
  int n = blockIdx.x * blockDim.x + threadIdx.x;
  if (n >= N) return;
  int beg = rowptr[n], end = rowptr[n + 1];
  float m = -1e30f;
  for (int j = beg; j < end; ++j) m = fmaxf(m, e2[j]);
  float s = 0.f;
  for (int j = beg; j < end; ++j) s += __expf(e2[j] - m);
  m2[n] = m;
  rs2[n] = 1.f / (s + SM_EPS);
}

// ---------------- layer-1 gather (bf16 h1 -> bf16 act1), fuses +b1, ELU ----------------
__global__ __launch_bounds__(256) void gather1_kernel(const u16* __restrict__ h1b,
                                                      const int* __restrict__ rowptr,
                                                      const int* __restrict__ srcs,
                                                      const float* __restrict__ e1,
                                                      const float* __restrict__ m1,
                                                      const float* __restrict__ rs1,
                                                      const float* __restrict__ b1,
                                                      u16* __restrict__ act1b, int N) {
  const int wave = threadIdx.x >> 6, lane = threadIdx.x & 63;
  const int n = blockIdx.x * 4 + wave;
  if (n >= N) return;
  const int h = lane >> 4;
  const int beg = rowptr[n], end = rowptr[n + 1];
  const float m = m1[(size_t)n * 4 + h];
  const float rs = rs1[(size_t)n * 4 + h];
  float4 acc = make_float4(0.f, 0.f, 0.f, 0.f);
  int j = beg;
  for (; j + 1 < end; j += 2) {
    int s0 = srcs[j], s1 = srcs[j + 1];
    float w0 = __expf(e1[(size_t)j * 4 + h] - m) * rs;
    float w1 = __expf(e1[(size_t)(j + 1) * 4 + h] - m) * rs;
    ushort4 v0 = *reinterpret_cast<const ushort4*>(&h1b[(size_t)s0 * 256 + lane * 4]);
    ushort4 v1 = *reinterpret_cast<const ushort4*>(&h1b[(size_t)s1 * 256 + lane * 4]);
    acc.x = fmaf(w0, bf2f(v0.x), acc.x); acc.y = fmaf(w0, bf2f(v0.y), acc.y);
    acc.z = fmaf(w0, bf2f(v0.z), acc.z); acc.w = fmaf(w0, bf2f(v0.w), acc.w);
    acc.x = fmaf(w1, bf2f(v1.x), acc.x); acc.y = fmaf(w1, bf2f(v1.y), acc.y);
    acc.z = fmaf(w1, bf2f(v1.z), acc.z); acc.w = fmaf(w1, bf2f(v1.w), acc.w);
  }
  if (j < end) {
    int s0 = srcs[j];
    float w0 = __expf(e1[(size_t)j * 4 + h] - m) * rs;
    ushort4 v0 = *reinterpret_cast<const ushort4*>(&h1b[(size_t)s0 * 256 + lane * 4]);
    acc.x = fmaf(w0, bf2f(v0.x), acc.x); acc.y = fmaf(w0, bf2f(v0.y), acc.y);
    acc.z = fmaf(w0, bf2f(v0.z), acc.z); acc.w = fmaf(w0, bf2f(v0.w), acc.w);
  }
  float4 bb = *reinterpret_cast<const float4*>(&b1[lane * 4]);
  float4 o;
  o.x = acc.x + bb.x; o.y = acc.y + bb.y; o.z = acc.z + bb.z; o.w = acc.w + bb.w;
  o.x = o.x > 0.f ? o.x : __expf(o.x) - 1.f;
  o.y = o.y > 0.f ? o.y : __expf(o.y) - 1.f;
  o.z = o.z > 0.f ? o.z : __expf(o.z) - 1.f;
  o.w = o.w > 0.f ? o.w : __expf(o.w) - 1.f;
  ushort4 ov;
  ov.x = f2bf(o.x); ov.y = f2bf(o.y); ov.z = f2bf(o.z); ov.w = f2bf(o.w);
  *reinterpret_cast<ushort4*>(&act1b[(size_t)n * 256 + lane * 4]) = ov;
}

// ---------------- layer-2 gather (bf16 h2): 4 edges x 16 lanes x 4ch ----------------
__global__ __launch_bounds__(256) void gather2_kernel(const u16* __restrict__ h2b,
                                                      const int* __restrict__ rowptr,
                                                      const int* __restrict__ srcs,
                                                      const float* __restrict__ e2,
                                                      const float* __restrict__ m2,
                                                      const float* __restrict__ rs2,
                                                      const float* __restrict__ b2,
                                                      float* __restrict__ out, int N) {
  const int wave = threadIdx.x >> 6, lane = threadIdx.x & 63;
  const int n = blockIdx.x * 4 + wave;
  if (n >= N) return;
  const int g = lane >> 4;
  const int c4 = (lane & 15) * 4;
  const int beg = rowptr[n], end = rowptr[n + 1];
  const float m = m2[n], rs = rs2[n];
  float4 acc = make_float4(0.f, 0.f, 0.f, 0.f);
  for (int j0 = beg; j0 < end; j0 += 4) {
    int j = j0 + g;
    float w = 0.f;
    int s = 0;
    if (j < end) {
      s = srcs[j];
      w = __expf(e2[j] - m) * rs;
    }
    ushort4 v = *reinterpret_cast<const ushort4*>(&h2b[(size_t)s * 64 + c4]);
    acc.x = fmaf(w, bf2f(v.x), acc.x); acc.y = fmaf(w, bf2f(v.y), acc.y);
    acc.z = fmaf(w, bf2f(v.z), acc.z); acc.w = fmaf(w, bf2f(v.w), acc.w);
  }
#pragma unroll
  for (int off = 16; off <= 32; off <<= 1) {
    acc.x += __shfl_xor(acc.x, off);
    acc.y += __shfl_xor(acc.y, off);
    acc.z += __shfl_xor(acc.z, off);
    acc.w += __shfl_xor(acc.w, off);
  }
  if (lane < 16) {
    float4 bb = *reinterpret_cast<const float4*>(&b2[c4]);
    float4 o = make_float4(acc.x + bb.x, acc.y + bb.y, acc.z + bb.z, acc.w + bb.w);
    *reinterpret_cast<float4*>(&out[(size_t)n * 64 + c4]) = o;
  }
}

extern "C" void kernel_launch(void* const* d_in, const int* in_sizes, int n_in,
                              void* d_out, int out_size, void* d_ws, size_t ws_size,
                              hipStream_t stream) {
  const float* x      = (const float*)d_in[0];
  const int*   ei     = (const int*)d_in[1];
  const float* W1     = (const float*)d_in[2];
  const float* a_src1 = (const float*)d_in[3];
  const float* a_dst1 = (const float*)d_in[4];
  const float* b1     = (const float*)d_in[5];
  const float* W2     = (const float*)d_in[6];
  const float* a_src2 = (const float*)d_in[7];
  const float* a_dst2 = (const float*)d_in[8];
  const float* b2     = (const float*)d_in[9];
  float* out = (float*)d_out;

  const int N = in_sizes[0] / 256;  // 50000
  const int E = in_sizes[1] / 2;    // 800000
  const int Etot = E + N;

  char* ws = (char*)d_ws;
  size_t off = 0;
  auto alloc = [&](size_t bytes) -> void* {
    off = (off + 255) & ~(size_t)255;
    void* p = ws + off;
    off += bytes;
    return p;
  };
  u16*   h1b    = (u16*)alloc((size_t)N * 256 * 2);
  u16*   act1b  = (u16*)alloc((size_t)N * 256 * 2);
  u16*   h2b    = (u16*)alloc((size_t)N * 64 * 2);
  float* as1    = (float*)alloc((size_t)N * 4 * 4);
  float* ad1    = (float*)alloc((size_t)N * 4 * 4);
  float* m1     = (float*)alloc((size_t)N * 4 * 4);
  float* rs1    = (float*)alloc((size_t)N * 4 * 4);
  float* e1     = (float*)alloc((size_t)Etot * 4 * 4);
  int*   counts = (int*)alloc((size_t)N * 4);
  int*   rowptr = (int*)alloc((size_t)(N + 1) * 4);
  int*   cursor = (int*)alloc((size_t)N * 4);
  int*   srcs   = (int*)alloc((size_t)Etot * 4);
  int*   dsts   = (int*)alloc((size_t)Etot * 4);
  int*   bsums  = (int*)alloc((size_t)256 * 4);
  float* as2 = as1;
  float* ad2 = ad1;
  float* m2  = m1;
  float* rs2 = rs1;
  float* e2  = e1;
  (void)ws_size; (void)n_in; (void)out_size;

  // CSR build
  hipMemsetAsync(counts, 0, (size_t)N * 4, stream);
  int eblocks = (Etot + 255) / 256;
  count_kernel<<<eblocks, 256, 0, stream>>>(ei, E, N, counts);
  const int nb = (N + 1023) / 1024;
  blocksum_kernel<<<nb, 256, 0, stream>>>(counts, bsums, N);
  scanbsums_kernel<<<1, 64, 0, stream>>>(bsums, nb);
  scanfinal_kernel<<<nb, 256, 0, stream>>>(counts, bsums, rowptr, cursor, N);
  scatter_kernel<<<eblocks, 256, 0, stream>>>(ei, E, N, cursor, srcs, dsts);

  const int gblocks = (N + 63) / 64;

  // Layer 1: h1 = x @ W1^T  (MFMA, A fp32 converted in staging)
  gemm_mfma<256, 1, 4, 0><<<gblocks, 256, 0, stream>>>(x, W1, h1b, N);
  alphas1_kernel<<<(N + 3) / 4, 256, 0, stream>>>(h1b, a_src1, a_dst1, as1, ad1, N);
  logits1_kernel<<<eblocks, 256, 0, stream>>>(srcs, dsts, as1, ad1, e1, Etot);
  maxsum1_kernel<<<(N * 4 + 255) / 256, 256, 0, stream>>>(rowptr, e1, m1, rs1, N);
  gather1_kernel<<<(N + 3) / 4, 256, 0, stream>>>(h1b, rowptr, srcs, e1, m1, rs1, b1, act1b, N);

  // Layer 2: h2 = act1 @ W2^T  (MFMA, A bf16 direct)
  gemm_mfma<64, 2, 2, 1><<<gblocks, 256, 0, stream>>>(act1b, W2, h2b, N);
  alphas2_kernel<<<(N + 3) / 4, 256, 0, stream>>>(h2b, a_src2, a_dst2, as2, ad2, N);
  logits2_kernel<<<eblocks, 256, 0, stream>>>(srcs, dsts, as2, ad2, e2, Etot);
  maxsum2_kernel<<<(N + 255) / 256, 256, 0, stream>>>(rowptr, e2, m2, rs2, N);
  gather2_kernel<<<(N + 3) / 4, 256, 0, stream>>>(h2b, rowptr, srcs, e2, m2, rs2, b2, out, N);
}